// Round 1
// baseline (221.211 us; speedup 1.0000x reference)
//
#include <hip/hip_runtime.h>
#include <hip/hip_bf16.h>

typedef __attribute__((ext_vector_type(8))) short bf16x8;
typedef __attribute__((ext_vector_type(4))) float f32x4;
typedef __attribute__((ext_vector_type(8))) unsigned short u16x8;
typedef __attribute__((ext_vector_type(4))) unsigned short u16x4;

static __device__ __forceinline__ unsigned short f2bf(float f) {
  __hip_bfloat16 h = __float2bfloat16(f);
  union { __hip_bfloat16 h; unsigned short u; } cv; cv.h = h; return cv.u;
}
static __device__ __forceinline__ float bf2f(unsigned short u) {
  union { unsigned int u; float f; } cv; cv.u = ((unsigned int)u) << 16; return cv.f;
}

static __device__ __forceinline__ void gload16(const unsigned short* g, unsigned short* l) {
  __builtin_amdgcn_global_load_lds((const __attribute__((address_space(1))) void*)g,
                                   (__attribute__((address_space(3))) void*)l, 16, 0, 0);
}

#define BM 128
#define BN 128
#define BK 64

// D[M][N] = A[M][K] * BT[N][K]^T, optional bias (per-row / per-col), post-scale,
// output bf16 or fp32(+residual).  M,N multiples of 128, K multiple of 64.
__global__ __launch_bounds__(256, 2) void gemm_bt(
    const unsigned short* __restrict__ A,
    const unsigned short* __restrict__ B,
    long strideA, long strideB, long strideD,
    int K, int ldd,
    const float* __restrict__ bias, int bias_mode, float post_scale,
    int out_mode, void* __restrict__ D, const float* __restrict__ resid)
{
  __shared__ unsigned short lA[2][BM * BK];
  __shared__ unsigned short lB[2][BN * BK];
  const int tid = threadIdx.x;
  const int lane = tid & 63;
  const int wid = tid >> 6;
  const int bm = blockIdx.y * BM;
  const int bn = blockIdx.x * BN;
  const int bz = blockIdx.z;
  const unsigned short* Ab = A + (size_t)bz * strideA + (size_t)bm * K;
  const unsigned short* Bb = B + (size_t)bz * strideB + (size_t)bn * K;
  const int wr = wid >> 1, wc = wid & 1;

  f32x4 acc[4][4];
  #pragma unroll
  for (int i = 0; i < 4; ++i)
    #pragma unroll
    for (int j = 0; j < 4; ++j) acc[i][j] = (f32x4){0.f, 0.f, 0.f, 0.f};

  const int NT = K >> 6;

  auto stage = [&](int buf, int k0) {
    // A tile: 128x64 bf16 = 16KB = 1024 16B-blocks; source pre-swizzled so that
    // LDS stays linear but holds k-block (slot ^ (row&7)) at slot  (rule 21).
    #pragma unroll
    for (int j = 0; j < 4; ++j) {
      int bi = j * 256 + tid;
      int row = bi >> 3, slot = bi & 7;
      int kb = slot ^ (row & 7);
      gload16(Ab + (size_t)row * K + k0 + kb * 8, &lA[buf][(j * 256 + wid * 64) * 8]);
    }
    #pragma unroll
    for (int j = 0; j < 4; ++j) {
      int bi = j * 256 + tid;
      int row = bi >> 3, slot = bi & 7;
      int kb = slot ^ (row & 7);
      gload16(Bb + (size_t)row * K + k0 + kb * 8, &lB[buf][(j * 256 + wid * 64) * 8]);
    }
  };

  stage(0, 0);
  __syncthreads();
  int buf = 0;
  for (int t = 0; t < NT; ++t) {
    if (t + 1 < NT) stage(buf ^ 1, (t + 1) * BK);
    #pragma unroll
    for (int s = 0; s < 2; ++s) {
      bf16x8 af[4], bfr[4];
      #pragma unroll
      for (int mi = 0; mi < 4; ++mi) {
        int row = wr * 64 + mi * 16 + (lane & 15);
        int slot = (s * 4 + (lane >> 4)) ^ (row & 7);
        af[mi] = *(const bf16x8*)&lA[buf][row * 64 + slot * 8];
      }
      #pragma unroll
      for (int ni = 0; ni < 4; ++ni) {
        int row = wc * 64 + ni * 16 + (lane & 15);
        int slot = (s * 4 + (lane >> 4)) ^ (row & 7);
        bfr[ni] = *(const bf16x8*)&lB[buf][row * 64 + slot * 8];
      }
      #pragma unroll
      for (int mi = 0; mi < 4; ++mi)
        #pragma unroll
        for (int ni = 0; ni < 4; ++ni)
          acc[mi][ni] = __builtin_amdgcn_mfma_f32_16x16x32_bf16(af[mi], bfr[ni], acc[mi][ni], 0, 0, 0);
    }
    __syncthreads();
    buf ^= 1;
  }

  #pragma unroll
  for (int mi = 0; mi < 4; ++mi) {
    #pragma unroll
    for (int ni = 0; ni < 4; ++ni) {
      #pragma unroll
      for (int r = 0; r < 4; ++r) {
        int row = bm + wr * 64 + mi * 16 + ((lane >> 4) << 2) + r;
        int col = bn + wc * 64 + ni * 16 + (lane & 15);
        float v = acc[mi][ni][r];
        if (bias_mode == 1) v += bias[row];
        else if (bias_mode == 2) v += bias[col];
        v *= post_scale;
        size_t idx = (size_t)bz * strideD + (size_t)row * ldd + col;
        if (out_mode == 0) ((unsigned short*)D)[idx] = f2bf(v);
        else ((float*)D)[idx] = v + resid[idx];
      }
    }
  }
}

// GroupNorm over (16 ch x 1024 px) per (b,g); writes h TRANSPOSED: ht[b][n][c] bf16.
__global__ __launch_bounds__(256) void groupnorm_to_ht(
    const float* __restrict__ x, const float* __restrict__ gamma,
    const float* __restrict__ beta, unsigned short* __restrict__ ht)
{
  const int b = blockIdx.x >> 5;
  const int g = blockIdx.x & 31;
  const int tid = threadIdx.x, lane = tid & 63, wid = tid >> 6;
  const float* xg = x + ((size_t)b * 512 + g * 16) * 1024;
  float s = 0.f, ss = 0.f;
  #pragma unroll 4
  for (int it = 0; it < 64; ++it) {
    float v = xg[it * 256 + tid];
    s += v; ss += v * v;
  }
  #pragma unroll
  for (int o = 32; o; o >>= 1) { s += __shfl_xor(s, o); ss += __shfl_xor(ss, o); }
  __shared__ float red[8];
  if (lane == 0) { red[wid] = s; red[4 + wid] = ss; }
  __syncthreads();
  s = red[0] + red[1] + red[2] + red[3];
  ss = red[4] + red[5] + red[6] + red[7];
  const float mu = s * (1.f / 16384.f);
  const float var = ss * (1.f / 16384.f) - mu * mu;
  const float rsig = rsqrtf(var + 1e-5f);
  __shared__ unsigned short tile[16][1024];
  #pragma unroll 4
  for (int it = 0; it < 64; ++it) {
    int li = it * 256 + tid;
    int ci = li >> 10, n = li & 1023;
    int c = g * 16 + ci;
    float v = (xg[li] - mu) * rsig * gamma[c] + beta[c];
    tile[ci][n] = f2bf(v);
  }
  __syncthreads();
  unsigned short* hb = ht + (size_t)b * 1024 * 512 + g * 16;
  for (int rep = 0; rep < 4; ++rep) {
    int n = rep * 256 + tid;
    u16x8 lo, hi;
    #pragma unroll
    for (int ci = 0; ci < 8; ++ci) lo[ci] = tile[ci][n];
    #pragma unroll
    for (int ci = 0; ci < 8; ++ci) hi[ci] = tile[8 + ci][n];
    *(u16x8*)&hb[(size_t)n * 512] = lo;
    *(u16x8*)&hb[(size_t)n * 512 + 8] = hi;
  }
}

// Row softmax in place over 1024 bf16 logits; one wave per row.
__global__ __launch_bounds__(256) void softmax_rows(unsigned short* __restrict__ attn)
{
  int row = blockIdx.x * 4 + (threadIdx.x >> 6);
  int lane = threadIdx.x & 63;
  unsigned short* p = attn + (size_t)row * 1024;
  u16x8 c0 = *(const u16x8*)&p[lane * 8];
  u16x8 c1 = *(const u16x8*)&p[512 + lane * 8];
  float f[16];
  #pragma unroll
  for (int j = 0; j < 8; ++j) { f[j] = bf2f(c0[j]); f[8 + j] = bf2f(c1[j]); }
  float m = f[0];
  #pragma unroll
  for (int j = 1; j < 16; ++j) m = fmaxf(m, f[j]);
  #pragma unroll
  for (int o = 32; o; o >>= 1) m = fmaxf(m, __shfl_xor(m, o));
  float sum = 0.f;
  #pragma unroll
  for (int j = 0; j < 16; ++j) { f[j] = __expf(f[j] - m); sum += f[j]; }
  #pragma unroll
  for (int o = 32; o; o >>= 1) sum += __shfl_xor(sum, o);
  float inv = 1.0f / sum;
  #pragma unroll
  for (int j = 0; j < 8; ++j) { c0[j] = f2bf(f[j] * inv); c1[j] = f2bf(f[8 + j] * inv); }
  *(u16x8*)&p[lane * 8] = c0;
  *(u16x8*)&p[512 + lane * 8] = c1;
}

__global__ __launch_bounds__(256) void convert_weights(
    const float* __restrict__ wq, const float* __restrict__ wk,
    const float* __restrict__ wv, const float* __restrict__ wp,
    unsigned short* __restrict__ out)
{
  int t = blockIdx.x * 256 + threadIdx.x;   // 262144 threads, 1 float4 each
  int m = t >> 16;
  int off = (t & 65535) * 4;
  const float* src = m == 0 ? wq : m == 1 ? wk : m == 2 ? wv : wp;
  float4 v = *(const float4*)&src[off];
  u16x4 o = { f2bf(v.x), f2bf(v.y), f2bf(v.z), f2bf(v.w) };
  *(u16x4*)&out[(size_t)m * 262144 + off] = o;
}

extern "C" void kernel_launch(void* const* d_in, const int* in_sizes, int n_in,
                              void* d_out, int out_size, void* d_ws, size_t ws_size,
                              hipStream_t stream)
{
  const float* x     = (const float*)d_in[0];
  const float* gamma = (const float*)d_in[1];
  const float* beta  = (const float*)d_in[2];
  const float* wq    = (const float*)d_in[3];
  const float* bq    = (const float*)d_in[4];
  const float* wk    = (const float*)d_in[5];
  const float* bk    = (const float*)d_in[6];
  const float* wv    = (const float*)d_in[7];
  const float* bv    = (const float*)d_in[8];
  const float* wp    = (const float*)d_in[9];
  const float* bp    = (const float*)d_in[10];

  const int B = 16, C = 512, N = 1024;
  unsigned short* ws   = (unsigned short*)d_ws;
  unsigned short* w_bf = ws;                               // 4 * 512*512
  unsigned short* ht   = w_bf + 4 * 262144;                // [B][N][C]
  unsigned short* qt   = ht + (size_t)B * N * C;           // [B][N][C]
  unsigned short* kt   = qt + (size_t)B * N * C;           // [B][N][C]
  unsigned short* vv   = kt + (size_t)B * N * C;           // [B][C][N]
  unsigned short* attn = vv + (size_t)B * N * C;           // [B][N][N]
  unsigned short* ot   = attn + (size_t)B * N * (size_t)N; // [B][N][C]

  const float scale = 0.044194173824159216f; // 512^-0.5

  convert_weights<<<dim3(1024), dim3(256), 0, stream>>>(wq, wk, wv, wp, w_bf);
  groupnorm_to_ht<<<dim3(B * 32), dim3(256), 0, stream>>>(x, gamma, beta, ht);

  // qt[b][n][co] = scale*(ht x wq^T + bq):  A=ht, BT=wq
  gemm_bt<<<dim3(C / 128, N / 128, B), dim3(256), 0, stream>>>(
      ht, w_bf + 0 * 262144, (long)(N * C), 0L, (long)(N * C), C, C,
      bq, 2, scale, 0, (void*)qt, (const float*)nullptr);
  // kt[b][n][co] = ht x wk^T + bk
  gemm_bt<<<dim3(C / 128, N / 128, B), dim3(256), 0, stream>>>(
      ht, w_bf + 1 * 262144, (long)(N * C), 0L, (long)(N * C), C, C,
      bk, 2, 1.0f, 0, (void*)kt, (const float*)nullptr);
  // v[b][co][m] = wv x h + bv:  A=wv, BT=ht
  gemm_bt<<<dim3(N / 128, C / 128, B), dim3(256), 0, stream>>>(
      w_bf + 2 * 262144, ht, 0L, (long)(N * C), (long)(C * N), C, N,
      bv, 1, 1.0f, 0, (void*)vv, (const float*)nullptr);
  // logits[b][n][m] = qt x kt^T   (scale already folded into qt)
  gemm_bt<<<dim3(N / 128, N / 128, B), dim3(256), 0, stream>>>(
      qt, kt, (long)(N * C), (long)(N * C), (long)((size_t)N * N), C, N,
      (const float*)nullptr, 0, 1.0f, 0, (void*)attn, (const float*)nullptr);
  softmax_rows<<<dim3(B * N / 4), dim3(256), 0, stream>>>(attn);
  // ot[b][n][c] = attn x v^T:  A=attn (K=N), BT=v
  gemm_bt<<<dim3(C / 128, N / 128, B), dim3(256), 0, stream>>>(
      attn, vv, (long)((size_t)N * N), (long)(C * N), (long)(N * C), N, C,
      (const float*)nullptr, 0, 1.0f, 0, (void*)ot, (const float*)nullptr);
  // out[b][co][n] = wp x o + bp + x   (fp32, residual)
  gemm_bt<<<dim3(N / 128, C / 128, B), dim3(256), 0, stream>>>(
      w_bf + 3 * 262144, ot, 0L, (long)(N * C), (long)(C * N), C, N,
      bp, 1, 1.0f, 1, d_out, x);
}